// Round 5
// baseline (139.006 us; speedup 1.0000x reference)
//
#include <hip/hip_runtime.h>

// ChannelKiller: out[b,c,s] = (c==0) ? x[b,c,s] : 0
// x: [16, 8, 1048576] fp32. Channel row = 4 MiB, batch = 32 MiB.
// R5: zero ONLY channels 1..7 via 16 contiguous 28 MiB hipMemsetAsync nodes
// (rocclr fillBufferAligned path, measured ~6.8 TB/s pure-write), then copy
// channel 0 densely (64 MiB read + 64 MiB write). Removes R4's 64 MiB
// double-write of channel 0.

typedef float f32x4 __attribute__((ext_vector_type(4)));

#define S_LOG2 18   // float4 per channel row = 1048576/4 = 2^18

// One float4 per thread over channel-0 space: i in [0, 16*2^18).
// flat addr = batch*8*2^18 + within-row  (batch stride 2^21 float4).
__global__ __launch_bounds__(256)
void ChannelKiller_copy_kernel(const f32x4* __restrict__ x,
                               f32x4* __restrict__ out) {
    int i = blockIdx.x * blockDim.x + threadIdx.x;
    int addr = ((i >> S_LOG2) << (S_LOG2 + 3)) | (i & ((1 << S_LOG2) - 1));
    out[addr] = x[addr];
}

extern "C" void kernel_launch(void* const* d_in, const int* in_sizes, int n_in,
                              void* d_out, int out_size, void* d_ws, size_t ws_size,
                              hipStream_t stream) {
    const f32x4* x = (const f32x4*)d_in[0];
    f32x4* out = (f32x4*)d_out;

    const size_t CHB = (size_t)1048576 * 4;  // 4 MiB channel row
    const size_t BATCHB = 8 * CHB;           // 32 MiB batch

    // Phase 1: zero channels 1..7 of each batch (contiguous 28 MiB each).
    for (int b = 0; b < 16; ++b) {
        hipMemsetAsync((char*)d_out + (size_t)b * BATCHB + CHB, 0, 7 * CHB, stream);
    }

    // Phase 2: copy channel 0. 16 * 2^18 = 4194304 float4 = 16384 blocks x 256.
    ChannelKiller_copy_kernel<<<16384, 256, 0, stream>>>(x, out);
}